// Round 4
// baseline (557.154 us; speedup 1.0000x reference)
//
#include <hip/hip_runtime.h>
#include <hip/hip_fp16.h>

// GCN: 4 layers, N=50000, E=800000, C: 128->96->96->96->96
// r4: v0 gather (260us best, 192-thr fused) + preprocessing redesign.
// Replaced bin(est 4MB scatter)+fine(196-block LDS sort) with direct global
// counting sort by dst: hist -> 2-level scan -> scatter. Eliminates the est
// round-trip (~51MB partial-line write amp) and the underparallel fine_k.
// nodeord is now a GLOBAL degree sort (more uniform waves than per-bucket).
// Gather model (r2/r3 confirmed): per-CU outstanding-line (MSHR) x latency
// floor; ~40us/layer irreducible at fp16 96ch (3 lines/row). r2: L2-pinned
// chunking cut FETCH 73.5->24.8MB but ran 43% slower (2.5x line footprint).
// r3: 384-thr blocks neutral -> not wave-occupancy-capped.

#define NN 50000
#define NE 800000
#define K1 128
#define CH 96
#define NT 3125    // NN/16 row-tiles (exact)
#define NPB 196    // 256-node chunks for scans
#define NSLOT (NPB * 256)  // 50176 nodeord slots (pad = node 0, benign dup)
#define NBB 782    // hist blocks (NE/1024 rounded up)

typedef _Float16 v8h __attribute__((ext_vector_type(8)));
typedef _Float16 v4h __attribute__((ext_vector_type(4)));
typedef float f4 __attribute__((ext_vector_type(4)));
typedef unsigned short ushort_t;

static inline size_t al256(size_t x) { return (x + 255) & ~size_t(255); }

// ---------------- prep0: weight swizzle + zero all counters ----------------
__global__ __launch_bounds__(256) void prep0_k(const float* __restrict__ W1f,
                                               const float* __restrict__ W2f,
                                               const float* __restrict__ W3f,
                                               const float* __restrict__ W4f,
                                               _Float16* __restrict__ W1sw,
                                               _Float16* __restrict__ W2sw,
                                               _Float16* __restrict__ W3sw,
                                               _Float16* __restrict__ W4sw,
                                               int* __restrict__ deg,
                                               int* __restrict__ cur,
                                               int* __restrict__ dh,
                                               int* __restrict__ dcur,
                                               int* __restrict__ nodeord) {
    int id = blockIdx.x * 256 + threadIdx.x;
    if (id < NN) { deg[id] = 0; cur[id] = 0; }
    if (id < NSLOT) nodeord[id] = 0;
    if (id < 256) { dh[id] = 0; dcur[id] = 0; }

    const float* W;
    _Float16* Wsw;
    int K, lid;
    if (id < 3072) {            // 96*32
        W = W1f; Wsw = W1sw; K = K1; lid = id;
    } else {
        int r = id - 3072;
        if (r >= 3 * 2304) return;
        int wsel = r / 2304;
        lid = r % 2304;         // 96*24
        K = CH;
        W = (wsel == 0) ? W2f : (wsel == 1) ? W3f : W4f;
        Wsw = (wsel == 0) ? W2sw : (wsel == 1) ? W3sw : W4sw;
    }
    int kc = K / 4;
    int n = lid / kc, k0 = (lid % kc) * 4;
    v4h o;
    o.x = (_Float16)W[(k0 + 0) * 96 + n];
    o.y = (_Float16)W[(k0 + 1) * 96 + n];
    o.z = (_Float16)W[(k0 + 2) * 96 + n];
    o.w = (_Float16)W[(k0 + 3) * 96 + n];
    int off = (n >> 4) * (16 * K) + (k0 >> 3) * 128 + (n & 15) * 8 + (k0 & 7);
    *(v4h*)&Wsw[off] = o;
}

// ---------------- mix2: degree hist (blocks [0,NBB)) + layer-1 GEMM ---------
__global__ __launch_bounds__(256) void mix2_k(const int* __restrict__ dst,
                                              int* __restrict__ deg,
                                              const float* __restrict__ Xf,
                                              const _Float16* __restrict__ Wsw,
                                              _Float16* __restrict__ Hh) {
    __shared__ _Float16 smem[64 * K1];  // 16KB (gemm1 path only)
    int tid = threadIdx.x;

    if (blockIdx.x < NBB) {
        int base = blockIdx.x * 1024;
#pragma unroll
        for (int j = 0; j < 4; j++) {
            int i = base + j * 256 + tid;
            if (i < NE) atomicAdd(&deg[dst[i]], 1);
        }
        return;
    }

    // ---- gemm1 path ----
    int bid = blockIdx.x - NBB;
    constexpr int K = K1;
    constexpr int KK = K / 32;
    int wave = tid >> 6;
    int lane = tid & 63;
    int l15 = lane & 15, quad = lane >> 4;
    int t = bid * 4 + wave;

    int row0 = bid * 64;
    for (int i = tid; i < 64 * (K / 4); i += 256) {
        int r = i / (K / 4), c = i % (K / 4);
        int gr = row0 + r;
        float4 v = make_float4(0.f, 0.f, 0.f, 0.f);
        if (gr < NN) v = *(const float4*)&Xf[(size_t)gr * K + c * 4];
        int k0 = c * 4;
        v4h h;
        h.x = (_Float16)v.x; h.y = (_Float16)v.y;
        h.z = (_Float16)v.z; h.w = (_Float16)v.w;
        int off = (r >> 4) * (16 * K) + (k0 >> 3) * 128 + (r & 15) * 8 + (k0 & 7);
        *(v4h*)&smem[off] = h;
    }
    __syncthreads();

    v8h a[KK];
#pragma unroll
    for (int kk = 0; kk < KK; kk++) {
        int off = wave * (16 * K) + (kk * 4 + quad) * 128 + l15 * 8;
        a[kk] = *(v8h*)&smem[off];
    }

    f4 acc[6];
#pragma unroll
    for (int cb = 0; cb < 6; cb++) acc[cb] = {0.f, 0.f, 0.f, 0.f};

#pragma unroll
    for (int kk = 0; kk < KK; kk++) {
        v8h b[6];
#pragma unroll
        for (int cb = 0; cb < 6; cb++)
            b[cb] = ((const v8h*)Wsw)[cb * (2 * K) + (kk * 4 + quad) * 16 + l15];
#pragma unroll
        for (int cb = 0; cb < 6; cb++)
            acc[cb] = __builtin_amdgcn_mfma_f32_16x16x32_f16(b[cb], a[kk], acc[cb], 0, 0, 0);
    }

    if (t < NT) {
        int row = t * 16 + l15;
#pragma unroll
        for (int cb = 0; cb < 6; cb++) {
            v4h o;
            o.x = (_Float16)acc[cb].x;
            o.y = (_Float16)acc[cb].y;
            o.z = (_Float16)acc[cb].z;
            o.w = (_Float16)acc[cb].w;
            *(v4h*)&Hh[(size_t)row * 96 + cb * 16 + quad * 4] = o;
        }
    }
}

// ---------------- scana: per-chunk scan of deg -> local offs, bsum, dinv ----
__global__ __launch_bounds__(256) void scana_k(const int* __restrict__ deg,
                                               int* __restrict__ offs,
                                               float* __restrict__ dinv,
                                               int* __restrict__ bsum,
                                               int* __restrict__ dh) {
    __shared__ int sc[256];
    int b = blockIdx.x, t = threadIdx.x;
    int n = b * 256 + t;
    int v = (n < NN) ? deg[n] : 0;
    sc[t] = v;
    __syncthreads();
    for (int d = 1; d < 256; d <<= 1) {
        int x = (t >= d) ? sc[t - d] : 0;
        __syncthreads();
        sc[t] += x;
        __syncthreads();
    }
    if (n < NN) {
        offs[n] = sc[t] - v;               // local exclusive prefix
        dinv[n] = rsqrtf(1.0f + (float)v);
        int dm = (v > 255) ? 255 : v;
        atomicAdd(&dh[dm], 1);
    }
    if (t == 255) bsum[b] = sc[255];
}

// ---------------- finb: add chunk base to offs; degree-sorted nodeord -------
__global__ __launch_bounds__(256) void finb_k(const int* __restrict__ deg,
                                              const int* __restrict__ bsum,
                                              int* __restrict__ offs,
                                              const int* __restrict__ dh,
                                              int* __restrict__ dcur,
                                              int* __restrict__ nodeord) {
    __shared__ int sc[256];
    __shared__ int ob[256];
    __shared__ int dx[256];
    int b = blockIdx.x, t = threadIdx.x;
    // redundant per-block scan of bsum[196]
    int bv = (t < NPB) ? bsum[t] : 0;
    ob[t] = bv;
    sc[t] = bv;
    __syncthreads();
    for (int d = 1; d < 256; d <<= 1) {
        int x = (t >= d) ? sc[t - d] : 0;
        __syncthreads();
        sc[t] += x;
        __syncthreads();
    }
    int bbase = sc[b] - ob[b];   // exclusive prefix at chunk b
    __syncthreads();
    // redundant per-block scan of dh[256] -> exclusive dx
    int dv = dh[t];
    sc[t] = dv;
    __syncthreads();
    for (int d = 1; d < 256; d <<= 1) {
        int x = (t >= d) ? sc[t - d] : 0;
        __syncthreads();
        sc[t] += x;
        __syncthreads();
    }
    dx[t] = sc[t] - dv;
    __syncthreads();
    int n = b * 256 + t;
    if (n < NN) {
        offs[n] += bbase;
        int dg = deg[n];
        int dm = (dg > 255) ? 255 : dg;
        int slot = dx[dm] + atomicAdd(&dcur[dm], 1);
        nodeord[slot] = n;
    }
    if (n == 0) offs[NN] = NE;
}

// ---------------- scat: edge scatter into dst-sorted es ----------------
__global__ __launch_bounds__(256) void scat_k(const int* __restrict__ src,
                                              const int* __restrict__ dst,
                                              const int* __restrict__ offs,
                                              int* __restrict__ cur,
                                              ushort_t* __restrict__ es) {
    int i = blockIdx.x * 256 + threadIdx.x;
    if (i < NE) {
        int d = dst[i];
        int r = atomicAdd(&cur[d], 1);
        es[offs[d] + r] = (ushort_t)src[i];
    }
}

// ---------------- shared gather-accumulate helper ----------------
__device__ __forceinline__ void acc8(v8h h, float w, float* a) {
    a[0] = fmaf(w, (float)h.s0, a[0]);
    a[1] = fmaf(w, (float)h.s1, a[1]);
    a[2] = fmaf(w, (float)h.s2, a[2]);
    a[3] = fmaf(w, (float)h.s3, a[3]);
    a[4] = fmaf(w, (float)h.s4, a[4]);
    a[5] = fmaf(w, (float)h.s5, a[5]);
    a[6] = fmaf(w, (float)h.s6, a[6]);
    a[7] = fmaf(w, (float)h.s7, a[7]);
}

// 2-deep software-pipelined gather (round-8 exact): chunk=4; next chunk's
// index+row loads issue before current chunk's FMAs.
__device__ __forceinline__ void gather_node(const _Float16* __restrict__ Hh,
                                            const int* __restrict__ offs,
                                            const ushort_t* __restrict__ es,
                                            const float* __restrict__ dinv,
                                            const float* __restrict__ bias,
                                            int n, int c8, float* a) {
    const _Float16* Hc = Hh + c8 * 8;
    float di = dinv[n];
    int e0 = offs[n], e1 = offs[n + 1];
    int e = e0;
    int nfull = (e1 - e0) >> 2;
    if (nfull > 0) {
        int s0[4];
        float w0[4];
        v8h h0[4];
#pragma unroll
        for (int j = 0; j < 4; j++) s0[j] = es[e + j];
#pragma unroll
        for (int j = 0; j < 4; j++) h0[j] = *(const v8h*)&Hc[(size_t)s0[j] * 96];
#pragma unroll
        for (int j = 0; j < 4; j++) w0[j] = dinv[s0[j]] * di;
        e += 4;
        for (int c = 1; c < nfull; c++) {
            int s1[4];
            float w1[4];
            v8h h1[4];
#pragma unroll
            for (int j = 0; j < 4; j++) s1[j] = es[e + j];
#pragma unroll
            for (int j = 0; j < 4; j++) h1[j] = *(const v8h*)&Hc[(size_t)s1[j] * 96];
#pragma unroll
            for (int j = 0; j < 4; j++) w1[j] = dinv[s1[j]] * di;
            // consume previous chunk while this chunk's loads are in flight
#pragma unroll
            for (int j = 0; j < 4; j++) acc8(h0[j], w0[j], a);
#pragma unroll
            for (int j = 0; j < 4; j++) {
                w0[j] = w1[j];
                h0[j] = h1[j];
            }
            e += 4;
        }
#pragma unroll
        for (int j = 0; j < 4; j++) acc8(h0[j], w0[j], a);
    }
    for (; e < e1; e++) {
        int s0 = es[e];
        float w0 = dinv[s0] * di;
        v8h h0 = *(const v8h*)&Hc[(size_t)s0 * 96];
        acc8(h0, w0, a);
    }
    // self-loop + bias
    v8h hs = *(const v8h*)&Hc[(size_t)n * 96];
    acc8(hs, di * di, a);
    float4 bv0 = *(const float4*)&bias[c8 * 8];
    float4 bv1 = *(const float4*)&bias[c8 * 8 + 4];
    a[0] += bv0.x; a[1] += bv0.y; a[2] += bv0.z; a[3] += bv0.w;
    a[4] += bv1.x; a[5] += bv1.y; a[6] += bv1.z; a[7] += bv1.w;
}

// ---------------- fused: F = relu(agg(Hprev)+bias); Hnext = F @ W ------------
// atile uses rotate-swizzled rows: element off = kblk*128 + ((row+kblk)&15)*8.
__global__ __launch_bounds__(192) void fused_k(const _Float16* __restrict__ Hprev,
                                               const int* __restrict__ offs,
                                               const ushort_t* __restrict__ es,
                                               const float* __restrict__ dinv,
                                               const float* __restrict__ bias,
                                               const _Float16* __restrict__ Wsw,
                                               const int* __restrict__ nodeord,
                                               _Float16* __restrict__ Hnext) {
    __shared__ _Float16 atile[1536];  // 16 x 96 in MFMA-A swizzle (rotated)
    int tid = threadIdx.x;
    int g = tid / 12, c8 = tid % 12;
    int n = nodeord[blockIdx.x * 16 + g];
    float a[8] = {0.f, 0.f, 0.f, 0.f, 0.f, 0.f, 0.f, 0.f};
    gather_node(Hprev, offs, es, dinv, bias, n, c8, a);
    v8h o;
    o.s0 = (_Float16)fmaxf(a[0], 0.f); o.s1 = (_Float16)fmaxf(a[1], 0.f);
    o.s2 = (_Float16)fmaxf(a[2], 0.f); o.s3 = (_Float16)fmaxf(a[3], 0.f);
    o.s4 = (_Float16)fmaxf(a[4], 0.f); o.s5 = (_Float16)fmaxf(a[5], 0.f);
    o.s6 = (_Float16)fmaxf(a[6], 0.f); o.s7 = (_Float16)fmaxf(a[7], 0.f);
    *(v8h*)&atile[c8 * 128 + (((g + c8) & 15)) * 8] = o;
    __syncthreads();

    // MFMA phase: wave w handles col-blocks {2w, 2w+1}
    int wave = tid >> 6;
    int lane = tid & 63;
    int l15 = lane & 15, quad = lane >> 4;
    v8h af[3];
#pragma unroll
    for (int kk = 0; kk < 3; kk++) {
        int kblk = kk * 4 + quad;
        af[kk] = *(v8h*)&atile[kblk * 128 + (((l15 + kblk) & 15)) * 8];
    }
    int nrow = nodeord[blockIdx.x * 16 + l15];
#pragma unroll
    for (int c = 0; c < 2; c++) {
        int cb = wave * 2 + c;
        f4 acc = {0.f, 0.f, 0.f, 0.f};
#pragma unroll
        for (int kk = 0; kk < 3; kk++) {
            v8h bf = ((const v8h*)Wsw)[cb * 192 + (kk * 4 + quad) * 16 + l15];
            acc = __builtin_amdgcn_mfma_f32_16x16x32_f16(bf, af[kk], acc, 0, 0, 0);
        }
        v4h o2;
        o2.x = (_Float16)acc.x; o2.y = (_Float16)acc.y;
        o2.z = (_Float16)acc.z; o2.w = (_Float16)acc.w;
        *(v4h*)&Hnext[(size_t)nrow * 96 + cb * 16 + quad * 4] = o2;
    }
}

// ---------------- final aggregation -> fp32 out ----------------
__global__ __launch_bounds__(192) void aggf_k(const _Float16* __restrict__ Hh,
                                              const int* __restrict__ offs,
                                              const ushort_t* __restrict__ es,
                                              const float* __restrict__ dinv,
                                              const float* __restrict__ bias,
                                              const int* __restrict__ nodeord,
                                              float* __restrict__ out) {
    int tid = threadIdx.x;
    int g = tid / 12, c8 = tid % 12;
    int n = nodeord[blockIdx.x * 16 + g];
    float a[8] = {0.f, 0.f, 0.f, 0.f, 0.f, 0.f, 0.f, 0.f};
    gather_node(Hh, offs, es, dinv, bias, n, c8, a);
    float4 o0 = {a[0], a[1], a[2], a[3]};
    float4 o1 = {a[4], a[5], a[6], a[7]};
    *(float4*)&out[(size_t)n * 96 + c8 * 8] = o0;
    *(float4*)&out[(size_t)n * 96 + c8 * 8 + 4] = o1;
}

// ---------------- launch ----------------

extern "C" void kernel_launch(void* const* d_in, const int* in_sizes, int n_in,
                              void* d_out, int out_size, void* d_ws, size_t ws_size,
                              hipStream_t stream) {
    const float* x = (const float*)d_in[0];
    const int* ei = (const int*)d_in[1];
    const float* W1 = (const float*)d_in[2];
    const float* b1 = (const float*)d_in[3];
    const float* W2 = (const float*)d_in[4];
    const float* b2 = (const float*)d_in[5];
    const float* W3 = (const float*)d_in[6];
    const float* b3 = (const float*)d_in[7];
    const float* W4 = (const float*)d_in[8];
    const float* b4 = (const float*)d_in[9];
    float* out = (float*)d_out;

    const int* src = ei;
    const int* dst = ei + NE;

    char* ws = (char*)d_ws;
    size_t o = 0;
    _Float16* Ha = (_Float16*)(ws + o);   o += al256((size_t)NN * 96 * 2);
    _Float16* Hb = (_Float16*)(ws + o);   o += al256((size_t)NN * 96 * 2);
    _Float16* W1sw = (_Float16*)(ws + o); o += al256((size_t)96 * K1 * 2);
    _Float16* W2sw = (_Float16*)(ws + o); o += al256((size_t)96 * 96 * 2);
    _Float16* W3sw = (_Float16*)(ws + o); o += al256((size_t)96 * 96 * 2);
    _Float16* W4sw = (_Float16*)(ws + o); o += al256((size_t)96 * 96 * 2);
    ushort_t* es = (ushort_t*)(ws + o);   o += al256((size_t)NE * 2);
    int* offs = (int*)(ws + o);           o += al256((size_t)(NN + 1) * 4);
    float* dinv = (float*)(ws + o);       o += al256((size_t)NN * 4);
    int* deg = (int*)(ws + o);            o += al256((size_t)NN * 4);
    int* cur = (int*)(ws + o);            o += al256((size_t)NN * 4);
    int* bsum = (int*)(ws + o);           o += al256((size_t)NPB * 4);
    int* dh = (int*)(ws + o);             o += al256((size_t)256 * 4);
    int* dcur = (int*)(ws + o);           o += al256((size_t)256 * 4);
    int* nodeord = (int*)(ws + o);        o += al256((size_t)NSLOT * 4);

    const int NB_GEMM = (NT + 3) / 4;     // 782
    const int NB_AGG = NSLOT / 16;        // 3136

    // preprocessing + layer-1 GEMM
    prep0_k<<<NPB, 256, 0, stream>>>(W1, W2, W3, W4, W1sw, W2sw, W3sw, W4sw,
                                     deg, cur, dh, dcur, nodeord);
    mix2_k<<<NBB + NB_GEMM, 256, 0, stream>>>(dst, deg, x, W1sw, Ha);
    scana_k<<<NPB, 256, 0, stream>>>(deg, offs, dinv, bsum, dh);
    finb_k<<<NPB, 256, 0, stream>>>(deg, bsum, offs, dh, dcur, nodeord);
    scat_k<<<(NE + 255) / 256, 256, 0, stream>>>(src, dst, offs, cur, es);

    // fused layers: agg + bias + relu + next GEMM
    fused_k<<<NB_AGG, 192, 0, stream>>>(Ha, offs, es, dinv, b1, W2sw, nodeord, Hb);
    fused_k<<<NB_AGG, 192, 0, stream>>>(Hb, offs, es, dinv, b2, W3sw, nodeord, Ha);
    fused_k<<<NB_AGG, 192, 0, stream>>>(Ha, offs, es, dinv, b3, W4sw, nodeord, Hb);
    // final aggregation -> fp32 out
    aggf_k<<<NB_AGG, 192, 0, stream>>>(Hb, offs, es, dinv, b4, nodeord, out);
}

// Round 5
// 311.553 us; speedup vs baseline: 1.7883x; 1.7883x over previous
//
#include <hip/hip_runtime.h>
#include <hip/hip_fp16.h>

// GCN: 4 layers, N=50000, E=800000, C: 128->96->96->96->96
// r5: r4 counting-sort preprocessing with the contended-atomic fix.
// r4 lesson (counters): finb_k 135us @ 0.07% VALU = 50k global atomics into
// ~30 hot degree-bin counters (~27ns/same-address atomic serialization).
// Fix: per-chunk LDS degree hist -> dhc[bin][chunk] (bin-major) -> single
// 1024-thr block scans all 50176 entries -> per-chunk LDS placement.
// No global counter receives more than ~32 hits (deg/cur per-node: 16 avg).
// Gather path byte-identical to v0 (260.6us best): 192-thr fused_k/aggf_k,
// model = per-CU outstanding-line (MSHR) x latency floor, ~40us/layer.

#define NN 50000
#define NE 800000
#define K1 128
#define CH 96
#define NT 3125    // NN/16 row-tiles (exact)
#define NPB 196    // 256-node chunks for scans
#define NSLOT (NPB * 256)  // 50176 nodeord slots (pad = node 0, benign dup)
#define NBB 782    // hist blocks (NE/1024 rounded up)

typedef _Float16 v8h __attribute__((ext_vector_type(8)));
typedef _Float16 v4h __attribute__((ext_vector_type(4)));
typedef float f4 __attribute__((ext_vector_type(4)));
typedef unsigned short ushort_t;

static inline size_t al256(size_t x) { return (x + 255) & ~size_t(255); }

// ---------------- prep0: weight swizzle + zero counters/nodeord -------------
__global__ __launch_bounds__(256) void prep0_k(const float* __restrict__ W1f,
                                               const float* __restrict__ W2f,
                                               const float* __restrict__ W3f,
                                               const float* __restrict__ W4f,
                                               _Float16* __restrict__ W1sw,
                                               _Float16* __restrict__ W2sw,
                                               _Float16* __restrict__ W3sw,
                                               _Float16* __restrict__ W4sw,
                                               int* __restrict__ deg,
                                               int* __restrict__ cur,
                                               int* __restrict__ nodeord) {
    int id = blockIdx.x * 256 + threadIdx.x;
    if (id < NN) { deg[id] = 0; cur[id] = 0; }
    if (id < NSLOT) nodeord[id] = 0;

    const float* W;
    _Float16* Wsw;
    int K, lid;
    if (id < 3072) {            // 96*32
        W = W1f; Wsw = W1sw; K = K1; lid = id;
    } else {
        int r = id - 3072;
        if (r >= 3 * 2304) return;
        int wsel = r / 2304;
        lid = r % 2304;         // 96*24
        K = CH;
        W = (wsel == 0) ? W2f : (wsel == 1) ? W3f : W4f;
        Wsw = (wsel == 0) ? W2sw : (wsel == 1) ? W3sw : W4sw;
    }
    int kc = K / 4;
    int n = lid / kc, k0 = (lid % kc) * 4;
    v4h o;
    o.x = (_Float16)W[(k0 + 0) * 96 + n];
    o.y = (_Float16)W[(k0 + 1) * 96 + n];
    o.z = (_Float16)W[(k0 + 2) * 96 + n];
    o.w = (_Float16)W[(k0 + 3) * 96 + n];
    int off = (n >> 4) * (16 * K) + (k0 >> 3) * 128 + (n & 15) * 8 + (k0 & 7);
    *(v4h*)&Wsw[off] = o;
}

// ---------------- mix2: degree hist (blocks [0,NBB)) + layer-1 GEMM ---------
__global__ __launch_bounds__(256) void mix2_k(const int* __restrict__ dst,
                                              int* __restrict__ deg,
                                              const float* __restrict__ Xf,
                                              const _Float16* __restrict__ Wsw,
                                              _Float16* __restrict__ Hh) {
    __shared__ _Float16 smem[64 * K1];  // 16KB (gemm1 path only)
    int tid = threadIdx.x;

    if (blockIdx.x < NBB) {
        int base = blockIdx.x * 1024;
#pragma unroll
        for (int j = 0; j < 4; j++) {
            int i = base + j * 256 + tid;
            if (i < NE) atomicAdd(&deg[dst[i]], 1);
        }
        return;
    }

    // ---- gemm1 path ----
    int bid = blockIdx.x - NBB;
    constexpr int K = K1;
    constexpr int KK = K / 32;
    int wave = tid >> 6;
    int lane = tid & 63;
    int l15 = lane & 15, quad = lane >> 4;
    int t = bid * 4 + wave;

    int row0 = bid * 64;
    for (int i = tid; i < 64 * (K / 4); i += 256) {
        int r = i / (K / 4), c = i % (K / 4);
        int gr = row0 + r;
        float4 v = make_float4(0.f, 0.f, 0.f, 0.f);
        if (gr < NN) v = *(const float4*)&Xf[(size_t)gr * K + c * 4];
        int k0 = c * 4;
        v4h h;
        h.x = (_Float16)v.x; h.y = (_Float16)v.y;
        h.z = (_Float16)v.z; h.w = (_Float16)v.w;
        int off = (r >> 4) * (16 * K) + (k0 >> 3) * 128 + (r & 15) * 8 + (k0 & 7);
        *(v4h*)&smem[off] = h;
    }
    __syncthreads();

    v8h a[KK];
#pragma unroll
    for (int kk = 0; kk < KK; kk++) {
        int off = wave * (16 * K) + (kk * 4 + quad) * 128 + l15 * 8;
        a[kk] = *(v8h*)&smem[off];
    }

    f4 acc[6];
#pragma unroll
    for (int cb = 0; cb < 6; cb++) acc[cb] = {0.f, 0.f, 0.f, 0.f};

#pragma unroll
    for (int kk = 0; kk < KK; kk++) {
        v8h b[6];
#pragma unroll
        for (int cb = 0; cb < 6; cb++)
            b[cb] = ((const v8h*)Wsw)[cb * (2 * K) + (kk * 4 + quad) * 16 + l15];
#pragma unroll
        for (int cb = 0; cb < 6; cb++)
            acc[cb] = __builtin_amdgcn_mfma_f32_16x16x32_f16(b[cb], a[kk], acc[cb], 0, 0, 0);
    }

    if (t < NT) {
        int row = t * 16 + l15;
#pragma unroll
        for (int cb = 0; cb < 6; cb++) {
            v4h o;
            o.x = (_Float16)acc[cb].x;
            o.y = (_Float16)acc[cb].y;
            o.z = (_Float16)acc[cb].z;
            o.w = (_Float16)acc[cb].w;
            *(v4h*)&Hh[(size_t)row * 96 + cb * 16 + quad * 4] = o;
        }
    }
}

// ---------------- scan_k: per-chunk deg scan + LDS degree hist --------------
// offs[n] = local exclusive prefix; bsum[b] = chunk total; dinv;
// dhc[bin*196 + b] = count of bin in chunk (bin-major for global scan).
__global__ __launch_bounds__(256) void scan_k(const int* __restrict__ deg,
                                              int* __restrict__ offs,
                                              float* __restrict__ dinv,
                                              int* __restrict__ bsum,
                                              int* __restrict__ dhc) {
    __shared__ int sc[256];
    __shared__ int h[256];
    int b = blockIdx.x, t = threadIdx.x;
    int n = b * 256 + t;
    int v = (n < NN) ? deg[n] : 0;
    sc[t] = v;
    h[t] = 0;
    __syncthreads();
    for (int d = 1; d < 256; d <<= 1) {
        int x = (t >= d) ? sc[t - d] : 0;
        __syncthreads();
        sc[t] += x;
        __syncthreads();
    }
    if (n < NN) {
        offs[n] = sc[t] - v;               // local exclusive prefix
        dinv[n] = rsqrtf(1.0f + (float)v);
        int dm = (v > 255) ? 255 : v;
        atomicAdd(&h[dm], 1);              // LDS hist, <=256 hits total
    }
    if (t == 255) bsum[b] = sc[255];
    __syncthreads();
    dhc[t * NPB + b] = h[t];
}

// ---------------- scan2_k: one block scans dhc[50176] in place -------------
// 1024 thr x 49 elems = 50176. Exclusive prefix in bin-major order gives the
// global nodeord slot base for every (bin, chunk).
__global__ __launch_bounds__(1024) void scan2_k(int* __restrict__ dhc) {
    __shared__ int ps[1024];
    int t = threadIdx.x;
    int base = t * 49;
    int loc[49];
    int s = 0;
#pragma unroll
    for (int i = 0; i < 49; i++) {
        loc[i] = dhc[base + i];
        s += loc[i];
    }
    ps[t] = s;
    __syncthreads();
    for (int d = 1; d < 1024; d <<= 1) {
        int x = (t >= d) ? ps[t - d] : 0;
        __syncthreads();
        ps[t] += x;
        __syncthreads();
    }
    int ex = ps[t] - s;   // exclusive prefix of this thread's segment
#pragma unroll
    for (int i = 0; i < 49; i++) {
        dhc[base + i] = ex;
        ex += loc[i];
    }
}

// ---------------- fin2_k: offs fixup + nodeord placement (LDS only) ---------
__global__ __launch_bounds__(256) void fin2_k(const int* __restrict__ deg,
                                              const int* __restrict__ bsum,
                                              int* __restrict__ offs,
                                              const int* __restrict__ dhc,
                                              int* __restrict__ nodeord) {
    __shared__ int sc[256];
    __shared__ int ob[256];
    __shared__ int db[256];
    int b = blockIdx.x, t = threadIdx.x;
    // redundant per-block scan of bsum[196] -> chunk base for offs
    int bv = (t < NPB) ? bsum[t] : 0;
    ob[t] = bv;
    sc[t] = bv;
    // this chunk's per-bin global slot bases
    db[t] = dhc[t * NPB + b];
    __syncthreads();
    for (int d = 1; d < 256; d <<= 1) {
        int x = (t >= d) ? sc[t - d] : 0;
        __syncthreads();
        sc[t] += x;
        __syncthreads();
    }
    int bbase = sc[b] - ob[b];   // exclusive prefix at chunk b
    int n = b * 256 + t;
    if (n < NN) {
        offs[n] += bbase;
        int dg = deg[n];
        int dm = (dg > 255) ? 255 : dg;
        int slot = atomicAdd(&db[dm], 1);   // LDS atomic, <=256 hits
        nodeord[slot] = n;
    }
    if (n == 0) offs[NN] = NE;
}

// ---------------- scat: edge scatter into dst-sorted es ----------------
__global__ __launch_bounds__(256) void scat_k(const int* __restrict__ src,
                                              const int* __restrict__ dst,
                                              const int* __restrict__ offs,
                                              int* __restrict__ cur,
                                              ushort_t* __restrict__ es) {
    int i = blockIdx.x * 256 + threadIdx.x;
    if (i < NE) {
        int d = dst[i];
        int r = atomicAdd(&cur[d], 1);     // per-node counter, 16 avg hits
        es[offs[d] + r] = (ushort_t)src[i];
    }
}

// ---------------- shared gather-accumulate helper ----------------
__device__ __forceinline__ void acc8(v8h h, float w, float* a) {
    a[0] = fmaf(w, (float)h.s0, a[0]);
    a[1] = fmaf(w, (float)h.s1, a[1]);
    a[2] = fmaf(w, (float)h.s2, a[2]);
    a[3] = fmaf(w, (float)h.s3, a[3]);
    a[4] = fmaf(w, (float)h.s4, a[4]);
    a[5] = fmaf(w, (float)h.s5, a[5]);
    a[6] = fmaf(w, (float)h.s6, a[6]);
    a[7] = fmaf(w, (float)h.s7, a[7]);
}

// 2-deep software-pipelined gather (round-8 exact): chunk=4; next chunk's
// index+row loads issue before current chunk's FMAs.
__device__ __forceinline__ void gather_node(const _Float16* __restrict__ Hh,
                                            const int* __restrict__ offs,
                                            const ushort_t* __restrict__ es,
                                            const float* __restrict__ dinv,
                                            const float* __restrict__ bias,
                                            int n, int c8, float* a) {
    const _Float16* Hc = Hh + c8 * 8;
    float di = dinv[n];
    int e0 = offs[n], e1 = offs[n + 1];
    int e = e0;
    int nfull = (e1 - e0) >> 2;
    if (nfull > 0) {
        int s0[4];
        float w0[4];
        v8h h0[4];
#pragma unroll
        for (int j = 0; j < 4; j++) s0[j] = es[e + j];
#pragma unroll
        for (int j = 0; j < 4; j++) h0[j] = *(const v8h*)&Hc[(size_t)s0[j] * 96];
#pragma unroll
        for (int j = 0; j < 4; j++) w0[j] = dinv[s0[j]] * di;
        e += 4;
        for (int c = 1; c < nfull; c++) {
            int s1[4];
            float w1[4];
            v8h h1[4];
#pragma unroll
            for (int j = 0; j < 4; j++) s1[j] = es[e + j];
#pragma unroll
            for (int j = 0; j < 4; j++) h1[j] = *(const v8h*)&Hc[(size_t)s1[j] * 96];
#pragma unroll
            for (int j = 0; j < 4; j++) w1[j] = dinv[s1[j]] * di;
            // consume previous chunk while this chunk's loads are in flight
#pragma unroll
            for (int j = 0; j < 4; j++) acc8(h0[j], w0[j], a);
#pragma unroll
            for (int j = 0; j < 4; j++) {
                w0[j] = w1[j];
                h0[j] = h1[j];
            }
            e += 4;
        }
#pragma unroll
        for (int j = 0; j < 4; j++) acc8(h0[j], w0[j], a);
    }
    for (; e < e1; e++) {
        int s0 = es[e];
        float w0 = dinv[s0] * di;
        v8h h0 = *(const v8h*)&Hc[(size_t)s0 * 96];
        acc8(h0, w0, a);
    }
    // self-loop + bias
    v8h hs = *(const v8h*)&Hc[(size_t)n * 96];
    acc8(hs, di * di, a);
    float4 bv0 = *(const float4*)&bias[c8 * 8];
    float4 bv1 = *(const float4*)&bias[c8 * 8 + 4];
    a[0] += bv0.x; a[1] += bv0.y; a[2] += bv0.z; a[3] += bv0.w;
    a[4] += bv1.x; a[5] += bv1.y; a[6] += bv1.z; a[7] += bv1.w;
}

// ---------------- fused: F = relu(agg(Hprev)+bias); Hnext = F @ W ------------
// atile uses rotate-swizzled rows: element off = kblk*128 + ((row+kblk)&15)*8.
__global__ __launch_bounds__(192) void fused_k(const _Float16* __restrict__ Hprev,
                                               const int* __restrict__ offs,
                                               const ushort_t* __restrict__ es,
                                               const float* __restrict__ dinv,
                                               const float* __restrict__ bias,
                                               const _Float16* __restrict__ Wsw,
                                               const int* __restrict__ nodeord,
                                               _Float16* __restrict__ Hnext) {
    __shared__ _Float16 atile[1536];  // 16 x 96 in MFMA-A swizzle (rotated)
    int tid = threadIdx.x;
    int g = tid / 12, c8 = tid % 12;
    int n = nodeord[blockIdx.x * 16 + g];
    float a[8] = {0.f, 0.f, 0.f, 0.f, 0.f, 0.f, 0.f, 0.f};
    gather_node(Hprev, offs, es, dinv, bias, n, c8, a);
    v8h o;
    o.s0 = (_Float16)fmaxf(a[0], 0.f); o.s1 = (_Float16)fmaxf(a[1], 0.f);
    o.s2 = (_Float16)fmaxf(a[2], 0.f); o.s3 = (_Float16)fmaxf(a[3], 0.f);
    o.s4 = (_Float16)fmaxf(a[4], 0.f); o.s5 = (_Float16)fmaxf(a[5], 0.f);
    o.s6 = (_Float16)fmaxf(a[6], 0.f); o.s7 = (_Float16)fmaxf(a[7], 0.f);
    *(v8h*)&atile[c8 * 128 + (((g + c8) & 15)) * 8] = o;
    __syncthreads();

    // MFMA phase: wave w handles col-blocks {2w, 2w+1}
    int wave = tid >> 6;
    int lane = tid & 63;
    int l15 = lane & 15, quad = lane >> 4;
    v8h af[3];
#pragma unroll
    for (int kk = 0; kk < 3; kk++) {
        int kblk = kk * 4 + quad;
        af[kk] = *(v8h*)&atile[kblk * 128 + (((l15 + kblk) & 15)) * 8];
    }
    int nrow = nodeord[blockIdx.x * 16 + l15];
#pragma unroll
    for (int c = 0; c < 2; c++) {
        int cb = wave * 2 + c;
        f4 acc = {0.f, 0.f, 0.f, 0.f};
#pragma unroll
        for (int kk = 0; kk < 3; kk++) {
            v8h bf = ((const v8h*)Wsw)[cb * 192 + (kk * 4 + quad) * 16 + l15];
            acc = __builtin_amdgcn_mfma_f32_16x16x32_f16(bf, af[kk], acc, 0, 0, 0);
        }
        v4h o2;
        o2.x = (_Float16)acc.x; o2.y = (_Float16)acc.y;
        o2.z = (_Float16)acc.z; o2.w = (_Float16)acc.w;
        *(v4h*)&Hnext[(size_t)nrow * 96 + cb * 16 + quad * 4] = o2;
    }
}

// ---------------- final aggregation -> fp32 out ----------------
__global__ __launch_bounds__(192) void aggf_k(const _Float16* __restrict__ Hh,
                                              const int* __restrict__ offs,
                                              const ushort_t* __restrict__ es,
                                              const float* __restrict__ dinv,
                                              const float* __restrict__ bias,
                                              const int* __restrict__ nodeord,
                                              float* __restrict__ out) {
    int tid = threadIdx.x;
    int g = tid / 12, c8 = tid % 12;
    int n = nodeord[blockIdx.x * 16 + g];
    float a[8] = {0.f, 0.f, 0.f, 0.f, 0.f, 0.f, 0.f, 0.f};
    gather_node(Hh, offs, es, dinv, bias, n, c8, a);
    float4 o0 = {a[0], a[1], a[2], a[3]};
    float4 o1 = {a[4], a[5], a[6], a[7]};
    *(float4*)&out[(size_t)n * 96 + c8 * 8] = o0;
    *(float4*)&out[(size_t)n * 96 + c8 * 8 + 4] = o1;
}

// ---------------- launch ----------------

extern "C" void kernel_launch(void* const* d_in, const int* in_sizes, int n_in,
                              void* d_out, int out_size, void* d_ws, size_t ws_size,
                              hipStream_t stream) {
    const float* x = (const float*)d_in[0];
    const int* ei = (const int*)d_in[1];
    const float* W1 = (const float*)d_in[2];
    const float* b1 = (const float*)d_in[3];
    const float* W2 = (const float*)d_in[4];
    const float* b2 = (const float*)d_in[5];
    const float* W3 = (const float*)d_in[6];
    const float* b3 = (const float*)d_in[7];
    const float* W4 = (const float*)d_in[8];
    const float* b4 = (const float*)d_in[9];
    float* out = (float*)d_out;

    const int* src = ei;
    const int* dst = ei + NE;

    char* ws = (char*)d_ws;
    size_t o = 0;
    _Float16* Ha = (_Float16*)(ws + o);   o += al256((size_t)NN * 96 * 2);
    _Float16* Hb = (_Float16*)(ws + o);   o += al256((size_t)NN * 96 * 2);
    _Float16* W1sw = (_Float16*)(ws + o); o += al256((size_t)96 * K1 * 2);
    _Float16* W2sw = (_Float16*)(ws + o); o += al256((size_t)96 * 96 * 2);
    _Float16* W3sw = (_Float16*)(ws + o); o += al256((size_t)96 * 96 * 2);
    _Float16* W4sw = (_Float16*)(ws + o); o += al256((size_t)96 * 96 * 2);
    ushort_t* es = (ushort_t*)(ws + o);   o += al256((size_t)NE * 2);
    int* offs = (int*)(ws + o);           o += al256((size_t)(NN + 1) * 4);
    float* dinv = (float*)(ws + o);       o += al256((size_t)NN * 4);
    int* deg = (int*)(ws + o);            o += al256((size_t)NN * 4);
    int* cur = (int*)(ws + o);            o += al256((size_t)NN * 4);
    int* bsum = (int*)(ws + o);           o += al256((size_t)NPB * 4);
    int* dhc = (int*)(ws + o);            o += al256((size_t)256 * NPB * 4);
    int* nodeord = (int*)(ws + o);        o += al256((size_t)NSLOT * 4);

    const int NB_GEMM = (NT + 3) / 4;     // 782
    const int NB_AGG = NSLOT / 16;        // 3136

    // preprocessing + layer-1 GEMM
    prep0_k<<<NPB, 256, 0, stream>>>(W1, W2, W3, W4, W1sw, W2sw, W3sw, W4sw,
                                     deg, cur, nodeord);
    mix2_k<<<NBB + NB_GEMM, 256, 0, stream>>>(dst, deg, x, W1sw, Ha);
    scan_k<<<NPB, 256, 0, stream>>>(deg, offs, dinv, bsum, dhc);
    scan2_k<<<1, 1024, 0, stream>>>(dhc);
    fin2_k<<<NPB, 256, 0, stream>>>(deg, bsum, offs, dhc, nodeord);
    scat_k<<<(NE + 255) / 256, 256, 0, stream>>>(src, dst, offs, cur, es);

    // fused layers: agg + bias + relu + next GEMM
    fused_k<<<NB_AGG, 192, 0, stream>>>(Ha, offs, es, dinv, b1, W2sw, nodeord, Hb);
    fused_k<<<NB_AGG, 192, 0, stream>>>(Hb, offs, es, dinv, b2, W3sw, nodeord, Ha);
    fused_k<<<NB_AGG, 192, 0, stream>>>(Ha, offs, es, dinv, b3, W4sw, nodeord, Hb);
    // final aggregation -> fp32 out
    aggf_k<<<NB_AGG, 192, 0, stream>>>(Hb, offs, es, dinv, b4, nodeord, out);
}

// Round 6
// 249.480 us; speedup vs baseline: 2.2333x; 1.2488x over previous
//
#include <hip/hip_runtime.h>
#include <hip/hip_fp16.h>

// GCN: 4 layers, N=50000, E=800000, C: 128->96->96->96->96
// r6: v0 (260.6us best) with ONE change: mix_k's bin phase.
//  - bin blocks 1024 -> 4096 edges (196 blocks): bcnt slab-bump atomic depth
//    per counter 782 -> 196 (~27ns/same-addr atomic => ~21us -> ~5us).
//  - LDS counting sort by bucket, then CONTIGUOUS per-bucket run writes to
//    est (~84B avg) instead of random per-edge 4B scatter (r5 lesson: es/est
//    builds must end with coalesced writes from LDS).
// Everything else byte-identical to v0. Gather floor model (r2/r3): per-CU
// outstanding-line (MSHR) x latency; FETCH at compulsory 8-XCD optimum;
// fp16 96ch = exactly 3 aligned lines/row, irreducible; ~41us/layer.
// Prep critical path: bin(packed w/ gemm1) + fine(~15us). This attacks bin.

#define NN 50000
#define NE 800000
#define K1 128
#define CH 96
#define NT 3125    // NN/16 row-tiles (exact)
#define NPB 196    // dst buckets of 256 nodes
#define BCAP 5120  // slab capacity per bucket (mean 4082, ~16 sigma headroom)
#define NSLOT (NPB * 256)  // 50176 nodeord slots
#define NBBIN 196  // bin blocks (4096 edges each; 196*4096 >= NE)
#define EPB 4096   // edges per bin block

typedef _Float16 v8h __attribute__((ext_vector_type(8)));
typedef _Float16 v4h __attribute__((ext_vector_type(4)));
typedef float f4 __attribute__((ext_vector_type(4)));
typedef unsigned short ushort_t;
typedef unsigned char uchar_t;

static inline size_t al256(size_t x) { return (x + 255) & ~size_t(255); }

// ---------------- weight swizzle + bcnt zero ----------------
__global__ __launch_bounds__(256) void wconv_k(const float* __restrict__ W1f,
                                               const float* __restrict__ W2f,
                                               const float* __restrict__ W3f,
                                               const float* __restrict__ W4f,
                                               _Float16* __restrict__ W1sw,
                                               _Float16* __restrict__ W2sw,
                                               _Float16* __restrict__ W3sw,
                                               _Float16* __restrict__ W4sw,
                                               int* __restrict__ bcnt) {
    int id = blockIdx.x * 256 + threadIdx.x;
    if (id < NPB) bcnt[id] = 0;
    const float* W;
    _Float16* Wsw;
    int K, lid;
    if (id < 3072) {            // 96*32
        W = W1f; Wsw = W1sw; K = K1; lid = id;
    } else {
        int r = id - 3072;
        if (r >= 3 * 2304) return;
        int wsel = r / 2304;
        lid = r % 2304;         // 96*24
        K = CH;
        W = (wsel == 0) ? W2f : (wsel == 1) ? W3f : W4f;
        Wsw = (wsel == 0) ? W2sw : (wsel == 1) ? W3sw : W4sw;
    }
    int kc = K / 4;
    int n = lid / kc, k0 = (lid % kc) * 4;
    v4h o;
    o.x = (_Float16)W[(k0 + 0) * 96 + n];
    o.y = (_Float16)W[(k0 + 1) * 96 + n];
    o.z = (_Float16)W[(k0 + 2) * 96 + n];
    o.w = (_Float16)W[(k0 + 3) * 96 + n];
    int off = (n >> 4) * (16 * K) + (k0 >> 3) * 128 + (n & 15) * 8 + (k0 & 7);
    *(v4h*)&Wsw[off] = o;
}

// ---------------- mix: bin (blocks [0,NBBIN)) + layer-1 GEMM (rest) ---------
// bin: 4096 edges/block. LDS counting sort by bucket -> contiguous run
// writes into est slabs. One bcnt atomic per (block,bucket).
__global__ __launch_bounds__(256) void mix_k(const int* __restrict__ src,
                                             const int* __restrict__ dst,
                                             int* __restrict__ bcnt,
                                             int* __restrict__ est,
                                             const float* __restrict__ Xf,
                                             const _Float16* __restrict__ Wsw,
                                             _Float16* __restrict__ Hh) {
    __shared__ __align__(16) char smem_raw[23552];
    int tid = threadIdx.x;

    if (blockIdx.x < NBBIN) {
        int* h2 = (int*)smem_raw;               // [256] bucket counts -> cur
        int* start = h2 + 256;                  // [256] scan workspace/excl
        int* basel = start + 256;               // [256] global slab bases
        int* lout = basel + 256;                // [4096] sorted edge words
        uchar_t* bkt = (uchar_t*)(lout + 4096); // [4096] bucket per position
        int base = blockIdx.x * EPB;
        int total = NE - base;
        if (total > EPB) total = EPB;
        if (total < 0) total = 0;

        h2[tid] = 0;
        __syncthreads();
        // pass 1: bucket histogram
        for (int j = 0; j < EPB / 256; j++) {
            int i = base + j * 256 + tid;
            if (i < NE) atomicAdd(&h2[dst[i] >> 8], 1);
        }
        __syncthreads();
        int cnt = h2[tid];
        // exclusive scan of counts -> start
        start[tid] = cnt;
        __syncthreads();
        for (int d = 1; d < 256; d <<= 1) {
            int x = (tid >= d) ? start[tid - d] : 0;
            __syncthreads();
            start[tid] += x;
            __syncthreads();
        }
        int excl = start[tid] - cnt;
        __syncthreads();
        start[tid] = excl;
        // global slab base: one atomic per (block, nonzero bucket)
        if (tid < NPB && cnt > 0) basel[tid] = atomicAdd(&bcnt[tid], cnt);
        h2[tid] = 0;   // reuse as scatter rank counter
        __syncthreads();
        // pass 2: LDS scatter into bucket-sorted order
        for (int j = 0; j < EPB / 256; j++) {
            int i = base + j * 256 + tid;
            if (i < NE) {
                int s = src[i], d = dst[i];
                int bk = d >> 8;
                int r = atomicAdd(&h2[bk], 1);
                int p = start[bk] + r;
                lout[p] = s | ((d & 255) << 16);
                bkt[p] = (uchar_t)bk;
            }
        }
        __syncthreads();
        // pass 3: contiguous per-bucket run writes to est
        for (int j = 0; j < EPB / 256; j++) {
            int p = j * 256 + tid;
            if (p < total) {
                int bk = bkt[p];
                est[bk * BCAP + basel[bk] + (p - start[bk])] = lout[p];
            }
        }
        return;
    }

    // ---- gemm1 path ----
    _Float16* smem = (_Float16*)smem_raw;   // 16KB of the 23KB block
    int bid = blockIdx.x - NBBIN;
    constexpr int K = K1;
    constexpr int KK = K / 32;
    int wave = tid >> 6;
    int lane = tid & 63;
    int l15 = lane & 15, quad = lane >> 4;
    int t = bid * 4 + wave;

    int row0 = bid * 64;
    for (int i = tid; i < 64 * (K / 4); i += 256) {
        int r = i / (K / 4), c = i % (K / 4);
        int gr = row0 + r;
        float4 v = make_float4(0.f, 0.f, 0.f, 0.f);
        if (gr < NN) v = *(const float4*)&Xf[(size_t)gr * K + c * 4];
        int k0 = c * 4;
        v4h h;
        h.x = (_Float16)v.x; h.y = (_Float16)v.y;
        h.z = (_Float16)v.z; h.w = (_Float16)v.w;
        int off = (r >> 4) * (16 * K) + (k0 >> 3) * 128 + (r & 15) * 8 + (k0 & 7);
        *(v4h*)&smem[off] = h;
    }
    __syncthreads();

    v8h a[KK];
#pragma unroll
    for (int kk = 0; kk < KK; kk++) {
        int off = wave * (16 * K) + (kk * 4 + quad) * 128 + l15 * 8;
        a[kk] = *(v8h*)&smem[off];
    }

    f4 acc[6];
#pragma unroll
    for (int cb = 0; cb < 6; cb++) acc[cb] = {0.f, 0.f, 0.f, 0.f};

#pragma unroll
    for (int kk = 0; kk < KK; kk++) {
        v8h b[6];
#pragma unroll
        for (int cb = 0; cb < 6; cb++)
            b[cb] = ((const v8h*)Wsw)[cb * (2 * K) + (kk * 4 + quad) * 16 + l15];
#pragma unroll
        for (int cb = 0; cb < 6; cb++)
            acc[cb] = __builtin_amdgcn_mfma_f32_16x16x32_f16(b[cb], a[kk], acc[cb], 0, 0, 0);
    }

    if (t < NT) {
        int row = t * 16 + l15;
#pragma unroll
        for (int cb = 0; cb < 6; cb++) {
            v4h o;
            o.x = (_Float16)acc[cb].x;
            o.y = (_Float16)acc[cb].y;
            o.z = (_Float16)acc[cb].z;
            o.w = (_Float16)acc[cb].w;
            *(v4h*)&Hh[(size_t)row * 96 + cb * 16 + quad * 4] = o;
        }
    }
}

// ---------------- per-bucket sort (1024 thr); emit es/offs/dinv/nodeord ------
__global__ __launch_bounds__(1024) void fine_k(const int* __restrict__ est,
                                               const int* __restrict__ bcnt,
                                               ushort_t* __restrict__ es,
                                               int* __restrict__ offs,
                                               float* __restrict__ dinv,
                                               int* __restrict__ nodeord) {
    __shared__ ushort_t lsrc[BCAP];
    __shared__ unsigned char ldst[BCAP];
    __shared__ ushort_t lout[BCAP];
    __shared__ int sc[256];
    __shared__ int hist[256];
    __shared__ int cur[256];
    __shared__ int dh[256];

    int b = blockIdx.x;
    int tid = threadIdx.x;
    bool lead = tid < 256;

    // global bucket prefix: scan bcnt[0..NPB)
    if (lead) sc[tid] = (tid < NPB) ? bcnt[tid] : 0;
    __syncthreads();
    for (int d = 1; d < 256; d <<= 1) {
        int t = 0;
        if (lead && tid >= d) t = sc[tid - d];
        __syncthreads();
        if (lead) sc[tid] += t;
        __syncthreads();
    }
    int cnt = bcnt[b];
    if (cnt > BCAP) cnt = BCAP;
    int base = sc[b] - cnt;  // exclusive prefix for this bucket

    if (lead) hist[tid] = 0;
    __syncthreads();
    for (int j = tid; j < cnt; j += 1024) {
        int w = est[b * BCAP + j];
        lsrc[j] = (ushort_t)(w & 0xFFFF);
        int l = (w >> 16) & 255;
        ldst[j] = (unsigned char)l;
        atomicAdd(&hist[l], 1);
    }
    __syncthreads();
    int hv = lead ? hist[tid] : 0;
    if (lead) sc[tid] = hv;
    __syncthreads();
    for (int d = 1; d < 256; d <<= 1) {
        int t = 0;
        if (lead && tid >= d) t = sc[tid - d];
        __syncthreads();
        if (lead) sc[tid] += t;
        __syncthreads();
    }
    int nvalid = NN - (b << 8);
    if (nvalid > 256) nvalid = 256;
    if (lead) {
        int excl = sc[tid] - hv;
        int n = (b << 8) + tid;
        if (tid < nvalid) {
            offs[n] = base + excl;
            dinv[n] = rsqrtf(1.0f + (float)hv);
        }
        if (n == NN) offs[NN] = base + excl;  // == NE (last bucket)
        cur[tid] = excl;
        dh[tid] = 0;
    }
    __syncthreads();
    for (int j = tid; j < cnt; j += 1024) {
        int r = atomicAdd(&cur[ldst[j]], 1);
        lout[r] = lsrc[j];
    }
    if (lead) {
        int dv = (hv > 255) ? 255 : hv;
        if (tid < nvalid) atomicAdd(&dh[dv], 1);
    }
    __syncthreads();
    for (int j = tid; j < cnt; j += 1024) es[base + j] = lout[j];
    // degree-rank counting sort -> nodeord
    int dhv = lead ? dh[tid] : 0;
    if (lead) sc[tid] = dhv;
    __syncthreads();
    for (int d = 1; d < 256; d <<= 1) {
        int t = 0;
        if (lead && tid >= d) t = sc[tid - d];
        __syncthreads();
        if (lead) sc[tid] += t;
        __syncthreads();
    }
    if (lead) cur[tid] = sc[tid] - dhv;
    __syncthreads();
    if (lead) {
        int dv = (hv > 255) ? 255 : hv;
        if (tid < nvalid) {
            int slot = atomicAdd(&cur[dv], 1);
            nodeord[b * 256 + slot] = (b << 8) + tid;
        } else {
            nodeord[b * 256 + tid] = b << 8;  // safe duplicate
        }
    }
}

// ---------------- shared gather-accumulate helper ----------------
__device__ __forceinline__ void acc8(v8h h, float w, float* a) {
    a[0] = fmaf(w, (float)h.s0, a[0]);
    a[1] = fmaf(w, (float)h.s1, a[1]);
    a[2] = fmaf(w, (float)h.s2, a[2]);
    a[3] = fmaf(w, (float)h.s3, a[3]);
    a[4] = fmaf(w, (float)h.s4, a[4]);
    a[5] = fmaf(w, (float)h.s5, a[5]);
    a[6] = fmaf(w, (float)h.s6, a[6]);
    a[7] = fmaf(w, (float)h.s7, a[7]);
}

// 2-deep software-pipelined gather (round-8 exact): chunk=4; next chunk's
// index+row loads issue before current chunk's FMAs.
__device__ __forceinline__ void gather_node(const _Float16* __restrict__ Hh,
                                            const int* __restrict__ offs,
                                            const ushort_t* __restrict__ es,
                                            const float* __restrict__ dinv,
                                            const float* __restrict__ bias,
                                            int n, int c8, float* a) {
    const _Float16* Hc = Hh + c8 * 8;
    float di = dinv[n];
    int e0 = offs[n], e1 = offs[n + 1];
    int e = e0;
    int nfull = (e1 - e0) >> 2;
    if (nfull > 0) {
        int s0[4];
        float w0[4];
        v8h h0[4];
#pragma unroll
        for (int j = 0; j < 4; j++) s0[j] = es[e + j];
#pragma unroll
        for (int j = 0; j < 4; j++) h0[j] = *(const v8h*)&Hc[(size_t)s0[j] * 96];
#pragma unroll
        for (int j = 0; j < 4; j++) w0[j] = dinv[s0[j]] * di;
        e += 4;
        for (int c = 1; c < nfull; c++) {
            int s1[4];
            float w1[4];
            v8h h1[4];
#pragma unroll
            for (int j = 0; j < 4; j++) s1[j] = es[e + j];
#pragma unroll
            for (int j = 0; j < 4; j++) h1[j] = *(const v8h*)&Hc[(size_t)s1[j] * 96];
#pragma unroll
            for (int j = 0; j < 4; j++) w1[j] = dinv[s1[j]] * di;
            // consume previous chunk while this chunk's loads are in flight
#pragma unroll
            for (int j = 0; j < 4; j++) acc8(h0[j], w0[j], a);
#pragma unroll
            for (int j = 0; j < 4; j++) {
                w0[j] = w1[j];
                h0[j] = h1[j];
            }
            e += 4;
        }
#pragma unroll
        for (int j = 0; j < 4; j++) acc8(h0[j], w0[j], a);
    }
    for (; e < e1; e++) {
        int s0 = es[e];
        float w0 = dinv[s0] * di;
        v8h h0 = *(const v8h*)&Hc[(size_t)s0 * 96];
        acc8(h0, w0, a);
    }
    // self-loop + bias
    v8h hs = *(const v8h*)&Hc[(size_t)n * 96];
    acc8(hs, di * di, a);
    float4 bv0 = *(const float4*)&bias[c8 * 8];
    float4 bv1 = *(const float4*)&bias[c8 * 8 + 4];
    a[0] += bv0.x; a[1] += bv0.y; a[2] += bv0.z; a[3] += bv0.w;
    a[4] += bv1.x; a[5] += bv1.y; a[6] += bv1.z; a[7] += bv1.w;
}

// ---------------- fused: F = relu(agg(Hprev)+bias); Hnext = F @ W ------------
// atile uses rotate-swizzled rows: element off = kblk*128 + ((row+kblk)&15)*8.
__global__ __launch_bounds__(192) void fused_k(const _Float16* __restrict__ Hprev,
                                               const int* __restrict__ offs,
                                               const ushort_t* __restrict__ es,
                                               const float* __restrict__ dinv,
                                               const float* __restrict__ bias,
                                               const _Float16* __restrict__ Wsw,
                                               const int* __restrict__ nodeord,
                                               _Float16* __restrict__ Hnext) {
    __shared__ _Float16 atile[1536];  // 16 x 96 in MFMA-A swizzle (rotated)
    int tid = threadIdx.x;
    int g = tid / 12, c8 = tid % 12;
    int n = nodeord[blockIdx.x * 16 + g];
    float a[8] = {0.f, 0.f, 0.f, 0.f, 0.f, 0.f, 0.f, 0.f};
    gather_node(Hprev, offs, es, dinv, bias, n, c8, a);
    v8h o;
    o.s0 = (_Float16)fmaxf(a[0], 0.f); o.s1 = (_Float16)fmaxf(a[1], 0.f);
    o.s2 = (_Float16)fmaxf(a[2], 0.f); o.s3 = (_Float16)fmaxf(a[3], 0.f);
    o.s4 = (_Float16)fmaxf(a[4], 0.f); o.s5 = (_Float16)fmaxf(a[5], 0.f);
    o.s6 = (_Float16)fmaxf(a[6], 0.f); o.s7 = (_Float16)fmaxf(a[7], 0.f);
    *(v8h*)&atile[c8 * 128 + (((g + c8) & 15)) * 8] = o;
    __syncthreads();

    // MFMA phase: wave w handles col-blocks {2w, 2w+1}
    int wave = tid >> 6;
    int lane = tid & 63;
    int l15 = lane & 15, quad = lane >> 4;
    v8h af[3];
#pragma unroll
    for (int kk = 0; kk < 3; kk++) {
        int kblk = kk * 4 + quad;
        af[kk] = *(v8h*)&atile[kblk * 128 + (((l15 + kblk) & 15)) * 8];
    }
    int nrow = nodeord[blockIdx.x * 16 + l15];
#pragma unroll
    for (int c = 0; c < 2; c++) {
        int cb = wave * 2 + c;
        f4 acc = {0.f, 0.f, 0.f, 0.f};
#pragma unroll
        for (int kk = 0; kk < 3; kk++) {
            v8h bf = ((const v8h*)Wsw)[cb * 192 + (kk * 4 + quad) * 16 + l15];
            acc = __builtin_amdgcn_mfma_f32_16x16x32_f16(bf, af[kk], acc, 0, 0, 0);
        }
        v4h o2;
        o2.x = (_Float16)acc.x; o2.y = (_Float16)acc.y;
        o2.z = (_Float16)acc.z; o2.w = (_Float16)acc.w;
        *(v4h*)&Hnext[(size_t)nrow * 96 + cb * 16 + quad * 4] = o2;
    }
}

// ---------------- final aggregation -> fp32 out ----------------
__global__ __launch_bounds__(192) void aggf_k(const _Float16* __restrict__ Hh,
                                              const int* __restrict__ offs,
                                              const ushort_t* __restrict__ es,
                                              const float* __restrict__ dinv,
                                              const float* __restrict__ bias,
                                              const int* __restrict__ nodeord,
                                              float* __restrict__ out) {
    int tid = threadIdx.x;
    int g = tid / 12, c8 = tid % 12;
    int n = nodeord[blockIdx.x * 16 + g];
    float a[8] = {0.f, 0.f, 0.f, 0.f, 0.f, 0.f, 0.f, 0.f};
    gather_node(Hh, offs, es, dinv, bias, n, c8, a);
    float4 o0 = {a[0], a[1], a[2], a[3]};
    float4 o1 = {a[4], a[5], a[6], a[7]};
    *(float4*)&out[(size_t)n * 96 + c8 * 8] = o0;
    *(float4*)&out[(size_t)n * 96 + c8 * 8 + 4] = o1;
}

// ---------------- launch ----------------

extern "C" void kernel_launch(void* const* d_in, const int* in_sizes, int n_in,
                              void* d_out, int out_size, void* d_ws, size_t ws_size,
                              hipStream_t stream) {
    const float* x = (const float*)d_in[0];
    const int* ei = (const int*)d_in[1];
    const float* W1 = (const float*)d_in[2];
    const float* b1 = (const float*)d_in[3];
    const float* W2 = (const float*)d_in[4];
    const float* b2 = (const float*)d_in[5];
    const float* W3 = (const float*)d_in[6];
    const float* b3 = (const float*)d_in[7];
    const float* W4 = (const float*)d_in[8];
    const float* b4 = (const float*)d_in[9];
    float* out = (float*)d_out;

    const int* src = ei;
    const int* dst = ei + NE;

    char* ws = (char*)d_ws;
    size_t o = 0;
    _Float16* Ha = (_Float16*)(ws + o);   o += al256((size_t)NN * 96 * 2);
    _Float16* Hb = (_Float16*)(ws + o);   o += al256((size_t)NN * 96 * 2);
    _Float16* W1sw = (_Float16*)(ws + o); o += al256((size_t)96 * K1 * 2);
    _Float16* W2sw = (_Float16*)(ws + o); o += al256((size_t)96 * 96 * 2);
    _Float16* W3sw = (_Float16*)(ws + o); o += al256((size_t)96 * 96 * 2);
    _Float16* W4sw = (_Float16*)(ws + o); o += al256((size_t)96 * 96 * 2);
    int* est = (int*)(ws + o);            o += al256((size_t)NPB * BCAP * 4);
    ushort_t* es = (ushort_t*)(ws + o);   o += al256((size_t)NE * 2);
    int* offs = (int*)(ws + o);           o += al256((size_t)(NN + 1) * 4);
    float* dinv = (float*)(ws + o);       o += al256((size_t)NN * 4);
    int* bcnt = (int*)(ws + o);           o += al256((size_t)NPB * 4);
    int* nodeord = (int*)(ws + o);        o += al256((size_t)NSLOT * 4);

    const int NB_GEMM = (NT + 3) / 4;     // 782
    const int NB_AGG = NSLOT / 16;        // 3136

    // preprocessing + layer-1 GEMM
    wconv_k<<<39, 256, 0, stream>>>(W1, W2, W3, W4, W1sw, W2sw, W3sw, W4sw, bcnt);
    mix_k<<<NBBIN + NB_GEMM, 256, 0, stream>>>(src, dst, bcnt, est, x, W1sw, Ha);
    fine_k<<<NPB, 1024, 0, stream>>>(est, bcnt, es, offs, dinv, nodeord);

    // fused layers: agg + bias + relu + next GEMM
    fused_k<<<NB_AGG, 192, 0, stream>>>(Ha, offs, es, dinv, b1, W2sw, nodeord, Hb);
    fused_k<<<NB_AGG, 192, 0, stream>>>(Hb, offs, es, dinv, b2, W3sw, nodeord, Ha);
    fused_k<<<NB_AGG, 192, 0, stream>>>(Ha, offs, es, dinv, b3, W4sw, nodeord, Hb);
    // final aggregation -> fp32 out
    aggf_k<<<NB_AGG, 192, 0, stream>>>(Hb, offs, es, dinv, b4, nodeord, out);
}

// Round 7
// 248.091 us; speedup vs baseline: 2.2458x; 1.0056x over previous
//
#include <hip/hip_runtime.h>
#include <hip/hip_fp16.h>

// GCN: 4 layers, N=50000, E=800000, C: 128->96->96->96->96
// r7: r6 (249.5us best) with ONE concept changed: all 256-wide __syncthreads
// ladder scans (16 barriers each) replaced by wave __shfl_up scans + 2-level
// combine (3 barriers). Applied to fine_k (3 scans, ~48->9 barriers) and
// mix_k bin phase (1 scan). Everything else byte-identical to r6.
// Budget model: gather 4x41us = MSHR x latency floor (r2: L2-pinning slower;
// r3: occupancy neutral; r9: deeper pipeline neutral; FETCH at compulsory
// 8-XCD optimum). Prep ~54us is the attackable remainder; this targets its
// barrier serialization. If delta < 4us, prep is at practical floor ->
// next decision is fp8-H (2-line rows, -56us potential, absmax risk).

#define NN 50000
#define NE 800000
#define K1 128
#define CH 96
#define NT 3125    // NN/16 row-tiles (exact)
#define NPB 196    // dst buckets of 256 nodes
#define BCAP 5120  // slab capacity per bucket (mean 4082, ~16 sigma headroom)
#define NSLOT (NPB * 256)  // 50176 nodeord slots
#define NBBIN 196  // bin blocks (4096 edges each; 196*4096 >= NE)
#define EPB 4096   // edges per bin block

typedef _Float16 v8h __attribute__((ext_vector_type(8)));
typedef _Float16 v4h __attribute__((ext_vector_type(4)));
typedef float f4 __attribute__((ext_vector_type(4)));
typedef unsigned short ushort_t;
typedef unsigned char uchar_t;

static inline size_t al256(size_t x) { return (x + 255) & ~size_t(255); }

// exclusive prefix scan of v across the block (blockDim multiple of 64).
// tmp = LDS int[nw], nw = blockDim/64 (<=16). 3 barriers.
__device__ __forceinline__ int excl_scan(int v, int* tmp, int tid, int nw) {
    __syncthreads();                 // protect tmp reuse across calls
    int lane = tid & 63, w = tid >> 6;
    int x = v;
#pragma unroll
    for (int d = 1; d < 64; d <<= 1) {
        int y = __shfl_up(x, d, 64);
        if (lane >= d) x += y;
    }
    if (lane == 63) tmp[w] = x;
    __syncthreads();
    if (w == 0) {
        int s = (lane < nw) ? tmp[lane] : 0;
#pragma unroll
        for (int d = 1; d < 16; d <<= 1) {
            int y = __shfl_up(s, d, 64);
            if (lane >= d) s += y;
        }
        if (lane < nw) tmp[lane] = s;   // inclusive wave sums
    }
    __syncthreads();
    int base = (w > 0) ? tmp[w - 1] : 0;
    return base + x - v;
}

// ---------------- weight swizzle + bcnt zero ----------------
__global__ __launch_bounds__(256) void wconv_k(const float* __restrict__ W1f,
                                               const float* __restrict__ W2f,
                                               const float* __restrict__ W3f,
                                               const float* __restrict__ W4f,
                                               _Float16* __restrict__ W1sw,
                                               _Float16* __restrict__ W2sw,
                                               _Float16* __restrict__ W3sw,
                                               _Float16* __restrict__ W4sw,
                                               int* __restrict__ bcnt) {
    int id = blockIdx.x * 256 + threadIdx.x;
    if (id < NPB) bcnt[id] = 0;
    const float* W;
    _Float16* Wsw;
    int K, lid;
    if (id < 3072) {            // 96*32
        W = W1f; Wsw = W1sw; K = K1; lid = id;
    } else {
        int r = id - 3072;
        if (r >= 3 * 2304) return;
        int wsel = r / 2304;
        lid = r % 2304;         // 96*24
        K = CH;
        W = (wsel == 0) ? W2f : (wsel == 1) ? W3f : W4f;
        Wsw = (wsel == 0) ? W2sw : (wsel == 1) ? W3sw : W4sw;
    }
    int kc = K / 4;
    int n = lid / kc, k0 = (lid % kc) * 4;
    v4h o;
    o.x = (_Float16)W[(k0 + 0) * 96 + n];
    o.y = (_Float16)W[(k0 + 1) * 96 + n];
    o.z = (_Float16)W[(k0 + 2) * 96 + n];
    o.w = (_Float16)W[(k0 + 3) * 96 + n];
    int off = (n >> 4) * (16 * K) + (k0 >> 3) * 128 + (n & 15) * 8 + (k0 & 7);
    *(v4h*)&Wsw[off] = o;
}

// ---------------- mix: bin (blocks [0,NBBIN)) + layer-1 GEMM (rest) ---------
// bin: 4096 edges/block. LDS counting sort by bucket -> contiguous run
// writes into est slabs. One bcnt atomic per (block,bucket).
__global__ __launch_bounds__(256) void mix_k(const int* __restrict__ src,
                                             const int* __restrict__ dst,
                                             int* __restrict__ bcnt,
                                             int* __restrict__ est,
                                             const float* __restrict__ Xf,
                                             const _Float16* __restrict__ Wsw,
                                             _Float16* __restrict__ Hh) {
    __shared__ __align__(16) char smem_raw[23552];
    int tid = threadIdx.x;

    if (blockIdx.x < NBBIN) {
        int* h2 = (int*)smem_raw;               // [256] bucket counts -> cur
        int* start = h2 + 256;                  // [256] exclusive prefixes
        int* basel = start + 256;               // [256] global slab bases
        int* lout = basel + 256;                // [4096] sorted edge words
        uchar_t* bkt = (uchar_t*)(lout + 4096); // [4096] bucket per position
        int* stmp = (int*)bkt;                  // scan scratch (before pass2)
        int base = blockIdx.x * EPB;
        int total = NE - base;
        if (total > EPB) total = EPB;
        if (total < 0) total = 0;

        h2[tid] = 0;
        __syncthreads();
        // pass 1: bucket histogram
        for (int j = 0; j < EPB / 256; j++) {
            int i = base + j * 256 + tid;
            if (i < NE) atomicAdd(&h2[dst[i] >> 8], 1);
        }
        __syncthreads();
        int cnt = h2[tid];
        int excl = excl_scan(cnt, stmp, tid, 4);
        start[tid] = excl;
        // global slab base: one atomic per (block, nonzero bucket)
        if (tid < NPB && cnt > 0) basel[tid] = atomicAdd(&bcnt[tid], cnt);
        h2[tid] = 0;   // reuse as scatter rank counter
        __syncthreads();
        // pass 2: LDS scatter into bucket-sorted order
        for (int j = 0; j < EPB / 256; j++) {
            int i = base + j * 256 + tid;
            if (i < NE) {
                int s = src[i], d = dst[i];
                int bk = d >> 8;
                int r = atomicAdd(&h2[bk], 1);
                int p = start[bk] + r;
                lout[p] = s | ((d & 255) << 16);
                bkt[p] = (uchar_t)bk;
            }
        }
        __syncthreads();
        // pass 3: contiguous per-bucket run writes to est
        for (int j = 0; j < EPB / 256; j++) {
            int p = j * 256 + tid;
            if (p < total) {
                int bk = bkt[p];
                est[bk * BCAP + basel[bk] + (p - start[bk])] = lout[p];
            }
        }
        return;
    }

    // ---- gemm1 path ----
    _Float16* smem = (_Float16*)smem_raw;   // 16KB of the 23KB block
    int bid = blockIdx.x - NBBIN;
    constexpr int K = K1;
    constexpr int KK = K / 32;
    int wave = tid >> 6;
    int lane = tid & 63;
    int l15 = lane & 15, quad = lane >> 4;
    int t = bid * 4 + wave;

    int row0 = bid * 64;
    for (int i = tid; i < 64 * (K / 4); i += 256) {
        int r = i / (K / 4), c = i % (K / 4);
        int gr = row0 + r;
        float4 v = make_float4(0.f, 0.f, 0.f, 0.f);
        if (gr < NN) v = *(const float4*)&Xf[(size_t)gr * K + c * 4];
        int k0 = c * 4;
        v4h h;
        h.x = (_Float16)v.x; h.y = (_Float16)v.y;
        h.z = (_Float16)v.z; h.w = (_Float16)v.w;
        int off = (r >> 4) * (16 * K) + (k0 >> 3) * 128 + (r & 15) * 8 + (k0 & 7);
        *(v4h*)&smem[off] = h;
    }
    __syncthreads();

    v8h a[KK];
#pragma unroll
    for (int kk = 0; kk < KK; kk++) {
        int off = wave * (16 * K) + (kk * 4 + quad) * 128 + l15 * 8;
        a[kk] = *(v8h*)&smem[off];
    }

    f4 acc[6];
#pragma unroll
    for (int cb = 0; cb < 6; cb++) acc[cb] = {0.f, 0.f, 0.f, 0.f};

#pragma unroll
    for (int kk = 0; kk < KK; kk++) {
        v8h b[6];
#pragma unroll
        for (int cb = 0; cb < 6; cb++)
            b[cb] = ((const v8h*)Wsw)[cb * (2 * K) + (kk * 4 + quad) * 16 + l15];
#pragma unroll
        for (int cb = 0; cb < 6; cb++)
            acc[cb] = __builtin_amdgcn_mfma_f32_16x16x32_f16(b[cb], a[kk], acc[cb], 0, 0, 0);
    }

    if (t < NT) {
        int row = t * 16 + l15;
#pragma unroll
        for (int cb = 0; cb < 6; cb++) {
            v4h o;
            o.x = (_Float16)acc[cb].x;
            o.y = (_Float16)acc[cb].y;
            o.z = (_Float16)acc[cb].z;
            o.w = (_Float16)acc[cb].w;
            *(v4h*)&Hh[(size_t)row * 96 + cb * 16 + quad * 4] = o;
        }
    }
}

// ---------------- per-bucket sort (1024 thr); emit es/offs/dinv/nodeord ------
__global__ __launch_bounds__(1024) void fine_k(const int* __restrict__ est,
                                               const int* __restrict__ bcnt,
                                               ushort_t* __restrict__ es,
                                               int* __restrict__ offs,
                                               float* __restrict__ dinv,
                                               int* __restrict__ nodeord) {
    __shared__ ushort_t lsrc[BCAP];
    __shared__ unsigned char ldst[BCAP];
    __shared__ ushort_t lout[BCAP];
    __shared__ int hist[256];
    __shared__ int cur[256];
    __shared__ int dh[256];
    __shared__ int stmp[16];
    __shared__ int sbase[1];

    int b = blockIdx.x;
    int tid = threadIdx.x;
    bool lead = tid < 256;

    int cnt = bcnt[b];
    if (cnt > BCAP) cnt = BCAP;

    if (lead) { hist[tid] = 0; dh[tid] = 0; }
    // global bucket prefix: exclusive scan of bcnt[0..NPB)
    int bv = (tid < NPB) ? bcnt[tid] : 0;
    int bex = excl_scan(bv, stmp, tid, 16);  // entry barrier covers hist zero
    if (tid == b) sbase[0] = bex;
    __syncthreads();
    int base = sbase[0];

    // load est, build dst-local histogram
    for (int j = tid; j < cnt; j += 1024) {
        int w = est[b * BCAP + j];
        lsrc[j] = (ushort_t)(w & 0xFFFF);
        int l = (w >> 16) & 255;
        ldst[j] = (unsigned char)l;
        atomicAdd(&hist[l], 1);
    }
    __syncthreads();
    int hv = lead ? hist[tid] : 0;
    int hex = excl_scan(hv, stmp, tid, 16);
    int nvalid = NN - (b << 8);
    if (nvalid > 256) nvalid = 256;
    if (lead) {
        int n = (b << 8) + tid;
        if (tid < nvalid) {
            offs[n] = base + hex;
            dinv[n] = rsqrtf(1.0f + (float)hv);
        }
        if (n == NN) offs[NN] = base + hex;  // == NE (last bucket)
        cur[tid] = hex;
    }
    __syncthreads();
    // scatter into dst-local sorted order
    for (int j = tid; j < cnt; j += 1024) {
        int r = atomicAdd(&cur[ldst[j]], 1);
        lout[r] = lsrc[j];
    }
    if (lead) {
        int dv = (hv > 255) ? 255 : hv;
        if (tid < nvalid) atomicAdd(&dh[dv], 1);
    }
    __syncthreads();
    for (int j = tid; j < cnt; j += 1024) es[base + j] = lout[j];
    // degree-rank counting sort -> nodeord
    int dhv = lead ? dh[tid] : 0;
    int dhex = excl_scan(dhv, stmp, tid, 16);
    if (lead) cur[tid] = dhex;
    __syncthreads();
    if (lead) {
        int dv = (hv > 255) ? 255 : hv;
        if (tid < nvalid) {
            int slot = atomicAdd(&cur[dv], 1);
            nodeord[b * 256 + slot] = (b << 8) + tid;
        } else {
            nodeord[b * 256 + tid] = b << 8;  // safe duplicate
        }
    }
}

// ---------------- shared gather-accumulate helper ----------------
__device__ __forceinline__ void acc8(v8h h, float w, float* a) {
    a[0] = fmaf(w, (float)h.s0, a[0]);
    a[1] = fmaf(w, (float)h.s1, a[1]);
    a[2] = fmaf(w, (float)h.s2, a[2]);
    a[3] = fmaf(w, (float)h.s3, a[3]);
    a[4] = fmaf(w, (float)h.s4, a[4]);
    a[5] = fmaf(w, (float)h.s5, a[5]);
    a[6] = fmaf(w, (float)h.s6, a[6]);
    a[7] = fmaf(w, (float)h.s7, a[7]);
}

// 2-deep software-pipelined gather (round-8 exact): chunk=4; next chunk's
// index+row loads issue before current chunk's FMAs.
__device__ __forceinline__ void gather_node(const _Float16* __restrict__ Hh,
                                            const int* __restrict__ offs,
                                            const ushort_t* __restrict__ es,
                                            const float* __restrict__ dinv,
                                            const float* __restrict__ bias,
                                            int n, int c8, float* a) {
    const _Float16* Hc = Hh + c8 * 8;
    float di = dinv[n];
    int e0 = offs[n], e1 = offs[n + 1];
    int e = e0;
    int nfull = (e1 - e0) >> 2;
    if (nfull > 0) {
        int s0[4];
        float w0[4];
        v8h h0[4];
#pragma unroll
        for (int j = 0; j < 4; j++) s0[j] = es[e + j];
#pragma unroll
        for (int j = 0; j < 4; j++) h0[j] = *(const v8h*)&Hc[(size_t)s0[j] * 96];
#pragma unroll
        for (int j = 0; j < 4; j++) w0[j] = dinv[s0[j]] * di;
        e += 4;
        for (int c = 1; c < nfull; c++) {
            int s1[4];
            float w1[4];
            v8h h1[4];
#pragma unroll
            for (int j = 0; j < 4; j++) s1[j] = es[e + j];
#pragma unroll
            for (int j = 0; j < 4; j++) h1[j] = *(const v8h*)&Hc[(size_t)s1[j] * 96];
#pragma unroll
            for (int j = 0; j < 4; j++) w1[j] = dinv[s1[j]] * di;
            // consume previous chunk while this chunk's loads are in flight
#pragma unroll
            for (int j = 0; j < 4; j++) acc8(h0[j], w0[j], a);
#pragma unroll
            for (int j = 0; j < 4; j++) {
                w0[j] = w1[j];
                h0[j] = h1[j];
            }
            e += 4;
        }
#pragma unroll
        for (int j = 0; j < 4; j++) acc8(h0[j], w0[j], a);
    }
    for (; e < e1; e++) {
        int s0 = es[e];
        float w0 = dinv[s0] * di;
        v8h h0 = *(const v8h*)&Hc[(size_t)s0 * 96];
        acc8(h0, w0, a);
    }
    // self-loop + bias
    v8h hs = *(const v8h*)&Hc[(size_t)n * 96];
    acc8(hs, di * di, a);
    float4 bv0 = *(const float4*)&bias[c8 * 8];
    float4 bv1 = *(const float4*)&bias[c8 * 8 + 4];
    a[0] += bv0.x; a[1] += bv0.y; a[2] += bv0.z; a[3] += bv0.w;
    a[4] += bv1.x; a[5] += bv1.y; a[6] += bv1.z; a[7] += bv1.w;
}

// ---------------- fused: F = relu(agg(Hprev)+bias); Hnext = F @ W ------------
// atile uses rotate-swizzled rows: element off = kblk*128 + ((row+kblk)&15)*8.
__global__ __launch_bounds__(192) void fused_k(const _Float16* __restrict__ Hprev,
                                               const int* __restrict__ offs,
                                               const ushort_t* __restrict__ es,
                                               const float* __restrict__ dinv,
                                               const float* __restrict__ bias,
                                               const _Float16* __restrict__ Wsw,
                                               const int* __restrict__ nodeord,
                                               _Float16* __restrict__ Hnext) {
    __shared__ _Float16 atile[1536];  // 16 x 96 in MFMA-A swizzle (rotated)
    int tid = threadIdx.x;
    int g = tid / 12, c8 = tid % 12;
    int n = nodeord[blockIdx.x * 16 + g];
    float a[8] = {0.f, 0.f, 0.f, 0.f, 0.f, 0.f, 0.f, 0.f};
    gather_node(Hprev, offs, es, dinv, bias, n, c8, a);
    v8h o;
    o.s0 = (_Float16)fmaxf(a[0], 0.f); o.s1 = (_Float16)fmaxf(a[1], 0.f);
    o.s2 = (_Float16)fmaxf(a[2], 0.f); o.s3 = (_Float16)fmaxf(a[3], 0.f);
    o.s4 = (_Float16)fmaxf(a[4], 0.f); o.s5 = (_Float16)fmaxf(a[5], 0.f);
    o.s6 = (_Float16)fmaxf(a[6], 0.f); o.s7 = (_Float16)fmaxf(a[7], 0.f);
    *(v8h*)&atile[c8 * 128 + (((g + c8) & 15)) * 8] = o;
    __syncthreads();

    // MFMA phase: wave w handles col-blocks {2w, 2w+1}
    int wave = tid >> 6;
    int lane = tid & 63;
    int l15 = lane & 15, quad = lane >> 4;
    v8h af[3];
#pragma unroll
    for (int kk = 0; kk < 3; kk++) {
        int kblk = kk * 4 + quad;
        af[kk] = *(v8h*)&atile[kblk * 128 + (((l15 + kblk) & 15)) * 8];
    }
    int nrow = nodeord[blockIdx.x * 16 + l15];
#pragma unroll
    for (int c = 0; c < 2; c++) {
        int cb = wave * 2 + c;
        f4 acc = {0.f, 0.f, 0.f, 0.f};
#pragma unroll
        for (int kk = 0; kk < 3; kk++) {
            v8h bf = ((const v8h*)Wsw)[cb * 192 + (kk * 4 + quad) * 16 + l15];
            acc = __builtin_amdgcn_mfma_f32_16x16x32_f16(bf, af[kk], acc, 0, 0, 0);
        }
        v4h o2;
        o2.x = (_Float16)acc.x; o2.y = (_Float16)acc.y;
        o2.z = (_Float16)acc.z; o2.w = (_Float16)acc.w;
        *(v4h*)&Hnext[(size_t)nrow * 96 + cb * 16 + quad * 4] = o2;
    }
}

// ---------------- final aggregation -> fp32 out ----------------
__global__ __launch_bounds__(192) void aggf_k(const _Float16* __restrict__ Hh,
                                              const int* __restrict__ offs,
                                              const ushort_t* __restrict__ es,
                                              const float* __restrict__ dinv,
                                              const float* __restrict__ bias,
                                              const int* __restrict__ nodeord,
                                              float* __restrict__ out) {
    int tid = threadIdx.x;
    int g = tid / 12, c8 = tid % 12;
    int n = nodeord[blockIdx.x * 16 + g];
    float a[8] = {0.f, 0.f, 0.f, 0.f, 0.f, 0.f, 0.f, 0.f};
    gather_node(Hh, offs, es, dinv, bias, n, c8, a);
    float4 o0 = {a[0], a[1], a[2], a[3]};
    float4 o1 = {a[4], a[5], a[6], a[7]};
    *(float4*)&out[(size_t)n * 96 + c8 * 8] = o0;
    *(float4*)&out[(size_t)n * 96 + c8 * 8 + 4] = o1;
}

// ---------------- launch ----------------

extern "C" void kernel_launch(void* const* d_in, const int* in_sizes, int n_in,
                              void* d_out, int out_size, void* d_ws, size_t ws_size,
                              hipStream_t stream) {
    const float* x = (const float*)d_in[0];
    const int* ei = (const int*)d_in[1];
    const float* W1 = (const float*)d_in[2];
    const float* b1 = (const float*)d_in[3];
    const float* W2 = (const float*)d_in[4];
    const float* b2 = (const float*)d_in[5];
    const float* W3 = (const float*)d_in[6];
    const float* b3 = (const float*)d_in[7];
    const float* W4 = (const float*)d_in[8];
    const float* b4 = (const float*)d_in[9];
    float* out = (float*)d_out;

    const int* src = ei;
    const int* dst = ei + NE;

    char* ws = (char*)d_ws;
    size_t o = 0;
    _Float16* Ha = (_Float16*)(ws + o);   o += al256((size_t)NN * 96 * 2);
    _Float16* Hb = (_Float16*)(ws + o);   o += al256((size_t)NN * 96 * 2);
    _Float16* W1sw = (_Float16*)(ws + o); o += al256((size_t)96 * K1 * 2);
    _Float16* W2sw = (_Float16*)(ws + o); o += al256((size_t)96 * 96 * 2);
    _Float16* W3sw = (_Float16*)(ws + o); o += al256((size_t)96 * 96 * 2);
    _Float16* W4sw = (_Float16*)(ws + o); o += al256((size_t)96 * 96 * 2);
    int* est = (int*)(ws + o);            o += al256((size_t)NPB * BCAP * 4);
    ushort_t* es = (ushort_t*)(ws + o);   o += al256((size_t)NE * 2);
    int* offs = (int*)(ws + o);           o += al256((size_t)(NN + 1) * 4);
    float* dinv = (float*)(ws + o);       o += al256((size_t)NN * 4);
    int* bcnt = (int*)(ws + o);           o += al256((size_t)NPB * 4);
    int* nodeord = (int*)(ws + o);        o += al256((size_t)NSLOT * 4);

    const int NB_GEMM = (NT + 3) / 4;     // 782
    const int NB_AGG = NSLOT / 16;        // 3136

    // preprocessing + layer-1 GEMM
    wconv_k<<<39, 256, 0, stream>>>(W1, W2, W3, W4, W1sw, W2sw, W3sw, W4sw, bcnt);
    mix_k<<<NBBIN + NB_GEMM, 256, 0, stream>>>(src, dst, bcnt, est, x, W1sw, Ha);
    fine_k<<<NPB, 1024, 0, stream>>>(est, bcnt, es, offs, dinv, nodeord);

    // fused layers: agg + bias + relu + next GEMM
    fused_k<<<NB_AGG, 192, 0, stream>>>(Ha, offs, es, dinv, b1, W2sw, nodeord, Hb);
    fused_k<<<NB_AGG, 192, 0, stream>>>(Hb, offs, es, dinv, b2, W3sw, nodeord, Ha);
    fused_k<<<NB_AGG, 192, 0, stream>>>(Ha, offs, es, dinv, b3, W4sw, nodeord, Hb);
    // final aggregation -> fp32 out
    aggf_k<<<NB_AGG, 192, 0, stream>>>(Hb, offs, es, dinv, b4, nodeord, out);
}